// Round 3
// baseline (466.255 us; speedup 1.0000x reference)
//
#include <hip/hip_runtime.h>
#include <hip/hip_bf16.h>
#include <stdint.h>

// Problem constants (B=4, S=2048, H=1024, E=8, K=2)
#define E_    8
#define H_    1024
#define NTOK  8192           // B*S
#define KSEL  2
#define NSLOT (NTOK * KSEL)  // 16384

typedef __attribute__((ext_vector_type(8))) short   short8_t;  // 8 bf16 in 4 VGPRs
typedef __attribute__((ext_vector_type(4))) float   f32x4;

// GEMM tiling (256^2, 8 waves, m248 grouped-GEMM structure)
#define BM 256
#define BN 256
#define BK 64
#define MAXTILES 72   // ceil(NSLOT/BM) + (E-1) = 64 + 7, padded to 72

// ---- workspace layout (bytes) ----
#define CNT_OFF   0                        // 8 ints
#define CUR_OFF   64                       // 8 ints
#define OFFS_OFF  128                      // 9 ints
#define TOFF_OFF  256                      // 9 ints (tile prefix)
#define TOK_OFF   1024                     // NSLOT ints (64 KB)
#define WSL_OFF   (TOK_OFF + NSLOT * 4)    // NSLOT floats (64 KB)
#define AG_ROWS   (NSLOT + BM)             // +1 tile of padding for tail reads
#define AG_OFF    (1 << 18)                              // 256 KB
#define H1_OFF    (AG_OFF + AG_ROWS * H_ * 2)
#define W1T_OFF   (H1_OFF + AG_ROWS * H_ * 2)
#define W2T_OFF   (W1T_OFF + E_ * H_ * H_ * 2)

// ---------------------------------------------------------------------------
// async global->LDS, 16B per lane. LDS dst must be wave-uniform base.
__device__ __forceinline__ void async_copy16(const void* g, void* l) {
  __builtin_amdgcn_global_load_lds(
      (const __attribute__((address_space(1))) unsigned int*)g,
      (__attribute__((address_space(3))) unsigned int*)l,
      16, 0, 0);
}

// ---------------------------------------------------------------------------
__global__ void route_count(const int* __restrict__ idx, int* __restrict__ cnt) {
  int p = blockIdx.x * 256 + threadIdx.x;
  if (p < NSLOT) atomicAdd(&cnt[idx[p]], 1);
}

__global__ void route_scan(const int* __restrict__ cnt, int* __restrict__ offs,
                           int* __restrict__ cur, int* __restrict__ toff) {
  if (threadIdx.x == 0) {
    int s = 0, t = 0;
    for (int e = 0; e < E_; ++e) {
      offs[e] = s; cur[e] = s; toff[e] = t;
      s += cnt[e];
      t += (cnt[e] + BM - 1) / BM;
    }
    offs[E_] = s; toff[E_] = t;
  }
}

__global__ void route_scatter(const int* __restrict__ idx, const float* __restrict__ tkw,
                              int* __restrict__ cur, int* __restrict__ tok,
                              float* __restrict__ wsl) {
  int p = blockIdx.x * 256 + threadIdx.x;
  if (p < NSLOT) {
    int e = idx[p];
    int pos = atomicAdd(&cur[e], 1);
    tok[pos] = p >> 1;    // token id (K=2)
    wsl[pos] = tkw[p];
  }
}

// ---------------------------------------------------------------------------
// wt[e][f][h] = (bf16) w[e][h][f]   (K-contiguous layout for MFMA B fragments)
// blockIdx.z in [0,16): z<8 -> w1, z>=8 -> w2
__global__ void transpose_cast(const float* __restrict__ w1, const float* __restrict__ w2,
                               __hip_bfloat16* __restrict__ wt1, __hip_bfloat16* __restrict__ wt2) {
  __shared__ float t[32][33];
  const int z = blockIdx.z;
  const float* W = (z < E_ ? w1 : w2) + ((size_t)(z & 7) << 20);
  __hip_bfloat16* WT = (z < E_ ? wt1 : wt2) + ((size_t)(z & 7) << 20);
  const int h0 = blockIdx.y * 32, f0 = blockIdx.x * 32;
  const int tx = threadIdx.x, ty = threadIdx.y;  // 32 x 8
#pragma unroll
  for (int i = 0; i < 32; i += 8)
    t[ty + i][tx] = W[(size_t)(h0 + ty + i) * H_ + f0 + tx];
  __syncthreads();
#pragma unroll
  for (int i = 0; i < 32; i += 8)
    WT[(size_t)(f0 + ty + i) * H_ + h0 + tx] = __float2bfloat16(t[tx][ty + i]);
}

// ---------------------------------------------------------------------------
// Pack routed rows: Ag[p][:] = (bf16) x[tok[p]][:]
__global__ void gather_cast(const float* __restrict__ x, const int* __restrict__ tok,
                            __hip_bfloat16* __restrict__ Ag) {
  const int p = blockIdx.x;
  const int c = threadIdx.x;  // 256 threads, 4 elems each
  const int t = tok[p];
  float4 v = ((const float4*)(x + (size_t)t * H_))[c];
  union { __hip_bfloat16 h[4]; uint2 u; } cv;
  cv.h[0] = __float2bfloat16(v.x);
  cv.h[1] = __float2bfloat16(v.y);
  cv.h[2] = __float2bfloat16(v.z);
  cv.h[3] = __float2bfloat16(v.w);
  *reinterpret_cast<uint2*>(Ag + (size_t)p * H_ + (size_t)c * 4) = cv.u;
}

// ---------------------------------------------------------------------------
// Grouped GEMM, 256x256 tile, 8 waves (2x4), 2-phase dbuf pipeline (T3-min):
//   stage(next) -> compute(cur) -> vmcnt(0)+barrier   (ONE barrier per K-tile)
//   EPI=0: h1 = relu(A @ W^T + b)  -> bf16
//   EPI=1: out[tok[p]] += wsl[p] * (A @ W^T + b)   (f32 atomics)
template <int EPI>
__launch_bounds__(512, 2)
__global__ void moe_gemm(const __hip_bfloat16* __restrict__ Abase,
                         const __hip_bfloat16* __restrict__ Wt,   // [E][H][H] (f-major)
                         const float* __restrict__ bias,          // [E][H]
                         __hip_bfloat16* __restrict__ h1out,
                         float* __restrict__ out,
                         const int* __restrict__ cnt, const int* __restrict__ offs,
                         const int* __restrict__ toff,
                         const int* __restrict__ tok, const float* __restrict__ wsl) {
  const int bt = blockIdx.x;           // flat M-tile id across experts
  if (bt >= toff[E_]) return;
  int e = 0;
  while (bt >= toff[e + 1]) ++e;       // E=8, cheap scan
  const int mt = bt - toff[e];
  const int count = cnt[e];
  const int nt = blockIdx.y;

  const int tid = threadIdx.x;
  const int wid = tid >> 6, lane = tid & 63;
  const int wm = wid >> 2, wn = wid & 3;  // 2x4 waves -> per-wave 128x64 output

  const size_t Arow0 = (size_t)(offs[e] + mt * BM);
  const __hip_bfloat16* Aexp = Abase + Arow0 * H_;
  const __hip_bfloat16* Bexp = Wt + ((size_t)e << 20) + (size_t)(nt * BN) * H_;

  __shared__ __hip_bfloat16 smA[2][BM * BK];  // 32 KB each
  __shared__ __hip_bfloat16 smB[2][BN * BK];  // total 128 KB

  // staging map: issue i covers rows [i*64, i*64+64); thread -> row i*64+(tid>>3),
  // 16B at elem col (tid&7)*8. LDS linear: wave-uniform base + lane*16.
  const int srow  = tid >> 3;       // 0..63
  const int scol8 = (tid & 7) * 8;  // element offset within BK row

  f32x4 acc[8][4];
#pragma unroll
  for (int mi = 0; mi < 8; ++mi)
#pragma unroll
    for (int ni = 0; ni < 4; ++ni) acc[mi][ni] = f32x4{0.f, 0.f, 0.f, 0.f};

  auto stage = [&](int s, int kt) {
#pragma unroll
    for (int i = 0; i < 4; ++i)
      async_copy16(Aexp + (size_t)(i * 64 + srow) * H_ + kt * BK + scol8,
                   &smA[s][i * 4096 + wid * 512]);
#pragma unroll
    for (int i = 0; i < 4; ++i)
      async_copy16(Bexp + (size_t)(i * 64 + srow) * H_ + kt * BK + scol8,
                   &smB[s][i * 4096 + wid * 512]);
  };

  auto compute = [&](int s) {
#pragma unroll
    for (int ks = 0; ks < 2; ++ks) {
      short8_t a[8], b[4];
#pragma unroll
      for (int mi = 0; mi < 8; ++mi)
        a[mi] = *(const short8_t*)&smA[s][(wm * 128 + mi * 16 + (lane & 15)) * BK + ks * 32 + (lane >> 4) * 8];
#pragma unroll
      for (int ni = 0; ni < 4; ++ni)
        b[ni] = *(const short8_t*)&smB[s][(wn * 64 + ni * 16 + (lane & 15)) * BK + ks * 32 + (lane >> 4) * 8];
#pragma unroll
      for (int mi = 0; mi < 8; ++mi)
#pragma unroll
        for (int ni = 0; ni < 4; ++ni)
          acc[mi][ni] = __builtin_amdgcn_mfma_f32_16x16x32_bf16(a[mi], b[ni], acc[mi][ni], 0, 0, 0);
    }
  };

  const int KT = H_ / BK;  // 16
  stage(0, 0);
  __syncthreads();         // drains prologue vmcnt(0)
  int cur = 0;
  for (int kt = 0; kt < KT; ++kt) {
    if (kt + 1 < KT) stage(cur ^ 1, kt + 1);  // issue BEFORE compute: loads fly under MFMA
    compute(cur);
    __syncthreads();       // single per-tile barrier; compiler emits vmcnt(0) drain here
    cur ^= 1;
  }

  const int colb = nt * BN + wn * 64;
  if constexpr (EPI == 0) {
#pragma unroll
    for (int ni = 0; ni < 4; ++ni) {
      const int col = colb + ni * 16 + (lane & 15);
      const float bv = bias[e * H_ + col];
#pragma unroll
      for (int mi = 0; mi < 8; ++mi)
#pragma unroll
        for (int r = 0; r < 4; ++r) {
          const int lr = wm * 128 + mi * 16 + (lane >> 4) * 4 + r;
          if (mt * BM + lr < count) {
            float v = acc[mi][ni][r] + bv;
            h1out[(Arow0 + lr) * H_ + col] = __float2bfloat16(fmaxf(v, 0.f));
          }
        }
    }
  } else {
#pragma unroll
    for (int mi = 0; mi < 8; ++mi)
#pragma unroll
      for (int r = 0; r < 4; ++r) {
        const int lr = wm * 128 + mi * 16 + (lane >> 4) * 4 + r;
        if (mt * BM + lr < count) {
          const int p = (int)Arow0 + lr;
          const int t = tok[p];
          const float w = wsl[p];
#pragma unroll
          for (int ni = 0; ni < 4; ++ni) {
            const int col = colb + ni * 16 + (lane & 15);
            float v = (acc[mi][ni][r] + bias[e * H_ + col]) * w;
            atomicAdd(out + (size_t)t * H_ + col, v);
          }
        }
      }
  }
}

// ---------------------------------------------------------------------------
extern "C" void kernel_launch(void* const* d_in, const int* in_sizes, int n_in,
                              void* d_out, int out_size, void* d_ws, size_t ws_size,
                              hipStream_t stream) {
  const float* x   = (const float*)d_in[0];
  const int*   idx = (const int*)d_in[1];
  const float* tkw = (const float*)d_in[2];
  const float* w1  = (const float*)d_in[3];
  const float* b1  = (const float*)d_in[4];
  const float* w2  = (const float*)d_in[5];
  const float* b2  = (const float*)d_in[6];
  float* out = (float*)d_out;

  uint8_t* ws = (uint8_t*)d_ws;
  int*   cnt  = (int*)(ws + CNT_OFF);
  int*   cur  = (int*)(ws + CUR_OFF);
  int*   offs = (int*)(ws + OFFS_OFF);
  int*   toff = (int*)(ws + TOFF_OFF);
  int*   tok  = (int*)(ws + TOK_OFF);
  float* wsl  = (float*)(ws + WSL_OFF);
  __hip_bfloat16* Ag  = (__hip_bfloat16*)(ws + AG_OFF);
  __hip_bfloat16* h1  = (__hip_bfloat16*)(ws + H1_OFF);
  __hip_bfloat16* w1t = (__hip_bfloat16*)(ws + W1T_OFF);
  __hip_bfloat16* w2t = (__hip_bfloat16*)(ws + W2T_OFF);

  hipMemsetAsync(ws, 0, 1024, stream);                                // counters
  hipMemsetAsync(d_out, 0, (size_t)out_size * sizeof(float), stream); // output accum

  transpose_cast<<<dim3(H_ / 32, H_ / 32, 2 * E_), dim3(32, 8), 0, stream>>>(w1, w2, w1t, w2t);

  route_count<<<NSLOT / 256, 256, 0, stream>>>(idx, cnt);
  route_scan<<<1, 64, 0, stream>>>(cnt, offs, cur, toff);
  route_scatter<<<NSLOT / 256, 256, 0, stream>>>(idx, tkw, cur, tok, wsl);
  gather_cast<<<NSLOT, 256, 0, stream>>>(x, tok, Ag);

  moe_gemm<0><<<dim3(MAXTILES, H_ / BN), 512, 0, stream>>>(
      Ag, w1t, b1, h1, nullptr, cnt, offs, toff, tok, wsl);
  moe_gemm<1><<<dim3(MAXTILES, H_ / BN), 512, 0, stream>>>(
      h1, w2t, b2, nullptr, out, cnt, offs, toff, tok, wsl);
}

// Round 4
// 371.507 us; speedup vs baseline: 1.2550x; 1.2550x over previous
//
#include <hip/hip_runtime.h>
#include <hip/hip_bf16.h>
#include <stdint.h>

// Problem constants (B=4, S=2048, H=1024, E=8, K=2)
#define E_    8
#define H_    1024
#define NTOK  8192           // B*S
#define KSEL  2
#define NSLOT (NTOK * KSEL)  // 16384

typedef __attribute__((ext_vector_type(8))) short   short8_t;  // 8 bf16 in 4 VGPRs
typedef __attribute__((ext_vector_type(4))) float   f32x4;

// GEMM tiling: 128x128 tile, BK=64, 4 waves (2x2), dbuf LDS = 64KB -> 2 blocks/CU
#define BM 128
#define BN 128
#define BK 64
#define MAXMT 136            // max M-tiles: ceil(16384/128)=128 + 7 slack, padded to 136
#define NWG   (MAXMT * 8)    // 1088, divisible by 8 (bijective XCD swizzle)

// ---- workspace layout (bytes) ----
#define CNT_OFF   0                        // 8 ints
#define CUR_OFF   64                       // 8 ints
#define OFFS_OFF  128                      // 9 ints
#define TOFF_OFF  256                      // 9 ints (tile prefix)
#define TOK_OFF   1024                     // NSLOT ints (64 KB)
#define WSL_OFF   (TOK_OFF + NSLOT * 4)    // NSLOT floats (64 KB)
#define AG_ROWS   (NSLOT + 256)            // padding for tail-tile reads
#define AG_OFF    (1 << 18)                              // 256 KB
#define H1_OFF    (AG_OFF + AG_ROWS * H_ * 2)
#define W1T_OFF   (H1_OFF + AG_ROWS * H_ * 2)
#define W2T_OFF   (W1T_OF F + E_ * H_ * H_ * 2)
#undef W2T_OFF
#define W2T_OFF   (W1T_OFF + E_ * H_ * H_ * 2)

// ---------------------------------------------------------------------------
// async global->LDS, 16B per lane. LDS dst must be wave-uniform base + lane*16.
__device__ __forceinline__ void async_copy16(const void* g, void* l) {
  __builtin_amdgcn_global_load_lds(
      (const __attribute__((address_space(1))) unsigned int*)g,
      (__attribute__((address_space(3))) unsigned int*)l,
      16, 0, 0);
}

// ---------------------------------------------------------------------------
__global__ void route_count(const int* __restrict__ idx, int* __restrict__ cnt) {
  int p = blockIdx.x * 256 + threadIdx.x;
  if (p < NSLOT) atomicAdd(&cnt[idx[p]], 1);
}

__global__ void route_scan(const int* __restrict__ cnt, int* __restrict__ offs,
                           int* __restrict__ cur, int* __restrict__ toff) {
  if (threadIdx.x == 0) {
    int s = 0, t = 0;
    for (int e = 0; e < E_; ++e) {
      offs[e] = s; cur[e] = s; toff[e] = t;
      s += cnt[e];
      t += (cnt[e] + BM - 1) / BM;
    }
    offs[E_] = s; toff[E_] = t;
  }
}

__global__ void route_scatter(const int* __restrict__ idx, const float* __restrict__ tkw,
                              int* __restrict__ cur, int* __restrict__ tok,
                              float* __restrict__ wsl) {
  int p = blockIdx.x * 256 + threadIdx.x;
  if (p < NSLOT) {
    int e = idx[p];
    int pos = atomicAdd(&cur[e], 1);
    tok[pos] = p >> 1;    // token id (K=2)
    wsl[pos] = tkw[p];
  }
}

// ---------------------------------------------------------------------------
// wt[e][f][h] = (bf16) w[e][h][f]   (K-contiguous layout for MFMA B fragments)
// blockIdx.z in [0,16): z<8 -> w1, z>=8 -> w2
__global__ void transpose_cast(const float* __restrict__ w1, const float* __restrict__ w2,
                               __hip_bfloat16* __restrict__ wt1, __hip_bfloat16* __restrict__ wt2) {
  __shared__ float t[32][33];
  const int z = blockIdx.z;
  const float* W = (z < E_ ? w1 : w2) + ((size_t)(z & 7) << 20);
  __hip_bfloat16* WT = (z < E_ ? wt1 : wt2) + ((size_t)(z & 7) << 20);
  const int h0 = blockIdx.y * 32, f0 = blockIdx.x * 32;
  const int tx = threadIdx.x, ty = threadIdx.y;  // 32 x 8
#pragma unroll
  for (int i = 0; i < 32; i += 8)
    t[ty + i][tx] = W[(size_t)(h0 + ty + i) * H_ + f0 + tx];
  __syncthreads();
#pragma unroll
  for (int i = 0; i < 32; i += 8)
    WT[(size_t)(f0 + ty + i) * H_ + h0 + tx] = __float2bfloat16(t[tx][ty + i]);
}

// ---------------------------------------------------------------------------
// Pack routed rows: Ag[p][:] = (bf16) x[tok[p]][:]   (grid-stride over rows)
__global__ void gather_cast(const float* __restrict__ x, const int* __restrict__ tok,
                            __hip_bfloat16* __restrict__ Ag) {
  const int c = threadIdx.x;  // 256 threads, 4 elems each
  for (int p = blockIdx.x; p < NSLOT; p += gridDim.x) {
    const int t = tok[p];
    float4 v = ((const float4*)(x + (size_t)t * H_))[c];
    union { __hip_bfloat16 h[4]; uint2 u; } cv;
    cv.h[0] = __float2bfloat16(v.x);
    cv.h[1] = __float2bfloat16(v.y);
    cv.h[2] = __float2bfloat16(v.z);
    cv.h[3] = __float2bfloat16(v.w);
    *reinterpret_cast<uint2*>(Ag + (size_t)p * H_ + (size_t)c * 4) = cv.u;
  }
}

// ---------------------------------------------------------------------------
// Grouped GEMM, 128x128 tile, 4 waves (2x2), counted-vmcnt 2-phase pipeline
// (T3-min + T4 + T2 swizzle + T5 setprio + T1 XCD swizzle).
//   EPI=0: h1 = relu(A @ W^T + b)  -> bf16
//   EPI=1: out[tok[p]] += wsl[p] * (A @ W^T + b)   (f32 atomics)
template <int EPI>
__launch_bounds__(256, 2)
__global__ void moe_gemm(const __hip_bfloat16* __restrict__ Abase,
                         const __hip_bfloat16* __restrict__ Wt,   // [E][H][H] (f-major)
                         const float* __restrict__ bias,          // [E][H]
                         __hip_bfloat16* __restrict__ h1out,
                         float* __restrict__ out,
                         const int* __restrict__ cnt, const int* __restrict__ offs,
                         const int* __restrict__ toff,
                         const int* __restrict__ tok, const float* __restrict__ wsl) {
  // T1: bijective XCD swizzle (NWG % 8 == 0) -> consecutive work per XCD
  const int wgid = (blockIdx.x & 7) * (NWG / 8) + (blockIdx.x >> 3);
  const int bt = wgid >> 3;            // flat M-tile id across experts
  const int nt = wgid & 7;             // N-tile
  if (bt >= toff[E_]) return;
  int e = 0;
  while (bt >= toff[e + 1]) ++e;       // E=8, cheap scan
  const int mt = bt - toff[e];
  const int count = cnt[e];

  const int tid = threadIdx.x;
  const int wid = tid >> 6, lane = tid & 63;
  const int wm = wid >> 1, wn = wid & 1;  // 2x2 waves -> per-wave 64x64 output
  const int l15 = lane & 15, hi = lane >> 4, l7 = lane & 7;

  const size_t Arow0 = (size_t)(offs[e] + mt * BM);
  const __hip_bfloat16* Aexp = Abase + Arow0 * H_;
  const __hip_bfloat16* Bexp = Wt + ((size_t)e << 20) + (size_t)(nt * BN) * H_;

  __shared__ __hip_bfloat16 smA[2][BM * BK];  // 16 KB each
  __shared__ __hip_bfloat16 smB[2][BN * BK];  // total 64 KB -> 2 blocks/CU

  // ---- staging (T2 rule-21: linear LDS dest, inverse-swizzled global src) ----
  // thread -> phys (row = i*32 + tid>>3, unit = tid&7); logical col unit = unit ^ (row&7)
  const int srow = tid >> 3;                       // 0..31
  const int r3   = srow & 7;
  const int sue  = ((tid & 7) ^ r3) * 8;           // swizzled source element offset

  f32x4 acc[4][4];
#pragma unroll
  for (int mi = 0; mi < 4; ++mi)
#pragma unroll
    for (int ni = 0; ni < 4; ++ni) acc[mi][ni] = f32x4{0.f, 0.f, 0.f, 0.f};

  auto stage = [&](int s, int kt) {
#pragma unroll
    for (int i = 0; i < 4; ++i)
      async_copy16(Aexp + (size_t)(i * 32 + srow) * H_ + kt * BK + sue,
                   &smA[s][i * 2048 + tid * 8]);
#pragma unroll
    for (int i = 0; i < 4; ++i)
      async_copy16(Bexp + (size_t)(i * 32 + srow) * H_ + kt * BK + sue,
                   &smB[s][i * 2048 + tid * 8]);
  };

  // ds_read: logical (row, ul=ks*4+hi) lives at phys unit ul^(row&7); row&7 == l7
  const int pu0 = ((0 * 4 + hi) ^ l7) * 8;  // element offset, ks=0
  const int pu1 = ((1 * 4 + hi) ^ l7) * 8;  // ks=1

  auto compute = [&](int s) {
#pragma unroll
    for (int ks = 0; ks < 2; ++ks) {
      const int pu = ks ? pu1 : pu0;
      short8_t a[4], b[4];
#pragma unroll
      for (int mi = 0; mi < 4; ++mi)
        a[mi] = *(const short8_t*)&smA[s][(wm * 64 + mi * 16 + l15) * BK + pu];
#pragma unroll
      for (int ni = 0; ni < 4; ++ni)
        b[ni] = *(const short8_t*)&smB[s][(wn * 64 + ni * 16 + l15) * BK + pu];
#pragma unroll
      for (int mi = 0; mi < 4; ++mi)
#pragma unroll
        for (int ni = 0; ni < 4; ++ni)
          acc[mi][ni] = __builtin_amdgcn_mfma_f32_16x16x32_bf16(a[mi], b[ni], acc[mi][ni], 0, 0, 0);
    }
  };

  const int KT = H_ / BK;  // 16
  stage(0, 0);             // 8 loads in flight
  int cur = 0;
  for (int kt = 0; kt < KT; ++kt) {
    if (kt + 1 < KT) {
      stage(cur ^ 1, kt + 1);                          // 8 more loads: 16 outstanding
      asm volatile("s_waitcnt vmcnt(8)" ::: "memory"); // retire tile kt only (T4: never 0)
    } else {
      asm volatile("s_waitcnt vmcnt(0)" ::: "memory"); // epilogue drain
    }
    __builtin_amdgcn_s_barrier();        // all waves: tile kt resident
    __builtin_amdgcn_sched_barrier(0);   // rule 18: no ds_read hoisting above wait
    __builtin_amdgcn_s_setprio(1);       // T5
    compute(cur);
    __builtin_amdgcn_s_setprio(0);
    __builtin_amdgcn_sched_barrier(0);   // no ds_read sinking below barrier
    __builtin_amdgcn_s_barrier();        // buffer safe to overwrite next iter
    cur ^= 1;
  }

  const int colb = nt * BN + wn * 64;
  if constexpr (EPI == 0) {
#pragma unroll
    for (int ni = 0; ni < 4; ++ni) {
      const int col = colb + ni * 16 + l15;
      const float bv = bias[e * H_ + col];
#pragma unroll
      for (int mi = 0; mi < 4; ++mi)
#pragma unroll
        for (int r = 0; r < 4; ++r) {
          const int lr = wm * 64 + mi * 16 + hi * 4 + r;
          if (mt * BM + lr < count) {
            float v = acc[mi][ni][r] + bv;
            h1out[(Arow0 + lr) * H_ + col] = __float2bfloat16(fmaxf(v, 0.f));
          }
        }
    }
  } else {
#pragma unroll
    for (int mi = 0; mi < 4; ++mi)
#pragma unroll
      for (int r = 0; r < 4; ++r) {
        const int lr = wm * 64 + mi * 16 + hi * 4 + r;
        if (mt * BM + lr < count) {
          const int p = (int)Arow0 + lr;
          const int t = tok[p];
          const float w = wsl[p];
#pragma unroll
          for (int ni = 0; ni < 4; ++ni) {
            const int col = colb + ni * 16 + l15;
            float v = (acc[mi][ni][r] + bias[e * H_ + col]) * w;
            atomicAdd(out + (size_t)t * H_ + col, v);
          }
        }
      }
  }
}

// ---------------------------------------------------------------------------
extern "C" void kernel_launch(void* const* d_in, const int* in_sizes, int n_in,
                              void* d_out, int out_size, void* d_ws, size_t ws_size,
                              hipStream_t stream) {
  const float* x   = (const float*)d_in[0];
  const int*   idx = (const int*)d_in[1];
  const float* tkw = (const float*)d_in[2];
  const float* w1  = (const float*)d_in[3];
  const float* b1  = (const float*)d_in[4];
  const float* w2  = (const float*)d_in[5];
  const float* b2  = (const float*)d_in[6];
  float* out = (float*)d_out;

  uint8_t* ws = (uint8_t*)d_ws;
  int*   cnt  = (int*)(ws + CNT_OFF);
  int*   cur  = (int*)(ws + CUR_OFF);
  int*   offs = (int*)(ws + OFFS_OFF);
  int*   toff = (int*)(ws + TOFF_OFF);
  int*   tok  = (int*)(ws + TOK_OFF);
  float* wsl  = (float*)(ws + WSL_OFF);
  __hip_bfloat16* Ag  = (__hip_bfloat16*)(ws + AG_OFF);
  __hip_bfloat16* h1  = (__hip_bfloat16*)(ws + H1_OFF);
  __hip_bfloat16* w1t = (__hip_bfloat16*)(ws + W1T_OFF);
  __hip_bfloat16* w2t = (__hip_bfloat16*)(ws + W2T_OFF);

  hipMemsetAsync(ws, 0, 1024, stream);                                // counters
  hipMemsetAsync(d_out, 0, (size_t)out_size * sizeof(float), stream); // output accum

  transpose_cast<<<dim3(H_ / 32, H_ / 32, 2 * E_), dim3(32, 8), 0, stream>>>(w1, w2, w1t, w2t);

  route_count<<<NSLOT / 256, 256, 0, stream>>>(idx, cnt);
  route_scan<<<1, 64, 0, stream>>>(cnt, offs, cur, toff);
  route_scatter<<<NSLOT / 256, 256, 0, stream>>>(idx, tkw, cur, tok, wsl);
  gather_cast<<<2048, 256, 0, stream>>>(x, tok, Ag);

  moe_gemm<0><<<NWG, 256, 0, stream>>>(Ag, w1t, b1, h1, nullptr, cnt, offs, toff, tok, wsl);
  moe_gemm<1><<<NWG, 256, 0, stream>>>(h1, w2t, b2, nullptr, out, cnt, offs, toff, tok, wsl);
}